// Round 11
// baseline (278.682 us; speedup 1.0000x reference)
//
#include <hip/hip_runtime.h>
#include <cstddef>

#define N_NODES 50000
#define N_EDGES 400000
#define TOT_EDGES (N_EDGES + N_NODES)
#define M_PAD 50048    // 391 * 128  (GEMM row padding)
#define SCAN_PAD 50176 // 49 * 1024  (scan padding)
#define NBLK 49
#define CNT_BLKS 1758  // ceil(TOT_EDGES/256)

typedef _Float16 f16;
typedef __attribute__((ext_vector_type(8))) _Float16 f16x8;
typedef __attribute__((ext_vector_type(2))) _Float16 f16x2;
typedef __attribute__((ext_vector_type(4))) float f32x4;

__device__ __forceinline__ float lrelu(float e) { return e > 0.f ? e : 0.2f * e; }

// ---------------------------------------------------------------------------
__global__ void zero_int(int* __restrict__ p, int n) {
  int i = blockIdx.x * blockDim.x + threadIdx.x;
  if (i < n) p[i] = 0;
}

// blocks [0,CNT_BLKS): degree count; [CNT_BLKS, CNT_BLKS+768): weight prep
__global__ __launch_bounds__(256) void count_weights(
    const int* __restrict__ ei, int* __restrict__ deg,
    const float* __restrict__ W1, const float* __restrict__ W2,
    const float* __restrict__ att_s1, const float* __restrict__ att_d1,
    const float* __restrict__ att_s2, const float* __restrict__ att_d2,
    f16* __restrict__ w1t, f16* __restrict__ w2t,
    float* __restrict__ V1s, float* __restrict__ V1d,
    float* __restrict__ V2s, float* __restrict__ V2d) {
  const int b = blockIdx.x;
  if (b < CNT_BLKS) {
    const int e = b * 256 + threadIdx.x;
    if (e >= TOT_EDGES) return;
    const int dst = (e < N_EDGES) ? ei[N_EDGES + e] : (e - N_EDGES);
    atomicAdd(&deg[dst], 1);
    return;
  }
  const int bb = b - CNT_BLKS;
  if (bb < 256) {  // W1[128][512] -> w1t[512][128]
    const int idx = bb * 256 + threadIdx.x;
    const int cc = idx >> 7, rr = idx & 127;
    w1t[idx] = (f16)W1[(size_t)rr * 512 + cc];
  } else if (bb < 512) {  // W2[512][128] -> w2t[128][512]
    const int idx = (bb - 256) * 256 + threadIdx.x;
    const int cc = idx >> 9, rr = idx & 511;
    w2t[idx] = (f16)W2[(size_t)rr * 128 + cc];
  } else if (bb < 640) {  // V1
    const int wid = (bb - 512) * 4 + (threadIdx.x >> 6);
    const int lane = threadIdx.x & 63;
    const int k = wid >> 2, h = wid & 3;
    const float* wrow = W1 + (size_t)k * 512 + h * 128;
    float2 wv = *(const float2*)&wrow[lane * 2];
    float2 sv = *(const float2*)&att_s1[h * 128 + lane * 2];
    float2 dv = *(const float2*)&att_d1[h * 128 + lane * 2];
    float ps = wv.x * sv.x + wv.y * sv.y;
    float pd = wv.x * dv.x + wv.y * dv.y;
#pragma unroll
    for (int off = 32; off; off >>= 1) {
      ps += __shfl_xor(ps, off);
      pd += __shfl_xor(pd, off);
    }
    if (lane == 0) { V1s[k * 4 + h] = ps; V1d[k * 4 + h] = pd; }
  } else {  // V2
    const int wid = (bb - 640) * 4 + (threadIdx.x >> 6);
    const int lane = threadIdx.x & 63;
    const float* wrow = W2 + (size_t)wid * 128;
    float2 wv = *(const float2*)&wrow[lane * 2];
    float2 sv = *(const float2*)&att_s2[lane * 2];
    float2 dv = *(const float2*)&att_d2[lane * 2];
    float ps = wv.x * sv.x + wv.y * sv.y;
    float pd = wv.x * dv.x + wv.y * dv.y;
#pragma unroll
    for (int off = 32; off; off >>= 1) {
      ps += __shfl_xor(ps, off);
      pd += __shfl_xor(pd, off);
    }
    if (lane == 0) { V2s[wid] = ps; V2d[wid] = pd; }
  }
}

// blocks [0,NBLK): LDS degree histogram + block scan of deg (bsum = RAW totals);
// blocks [NBLK, NBLK+12512): prep_x (xb cvt, a1 = x.V1, aggb pad zero)
__global__ __launch_bounds__(256) void histscan_prepx(
    const int* __restrict__ deg, int* __restrict__ pre, int* __restrict__ bsum,
    int* __restrict__ blkcnt,
    const float* __restrict__ x, f16* __restrict__ xb,
    const float* __restrict__ V1s, const float* __restrict__ V1d,
    float* __restrict__ as1, float* __restrict__ ad1, f16* __restrict__ aggb) {
  __shared__ int wsum[4];
  __shared__ int lh[128];
  const int b = blockIdx.x;
  if (b < NBLK) {
    const int t = threadIdx.x, lane = t & 63, w = t >> 6;
    if (t < 128) lh[t] = 0;
    __syncthreads();
    const int base = b * 1024 + t * 4;
    int4 v = *(const int4*)&deg[base];
    if (base + 0 < N_NODES) atomicAdd(&lh[min(v.x, 127)], 1);
    if (base + 1 < N_NODES) atomicAdd(&lh[min(v.y, 127)], 1);
    if (base + 2 < N_NODES) atomicAdd(&lh[min(v.z, 127)], 1);
    if (base + 3 < N_NODES) atomicAdd(&lh[min(v.w, 127)], 1);
    const int s = v.x + v.y + v.z + v.w;
    int xx = s;
#pragma unroll
    for (int off = 1; off < 64; off <<= 1) {
      int y = __shfl_up(xx, off);
      if (lane >= off) xx += y;
    }
    if (lane == 63) wsum[w] = xx;
    __syncthreads();
    int woff = 0;
    for (int j = 0; j < w; ++j) woff += wsum[j];
    const int ex = xx - s + woff;
    pre[base + 0] = ex;
    pre[base + 1] = ex + v.x;
    pre[base + 2] = ex + v.x + v.y;
    pre[base + 3] = ex + v.x + v.y + v.z;
    if (t == 255) bsum[b] = ex + s;  // raw block total
    if (t < 128) blkcnt[t * NBLK + b] = lh[t];
    return;
  }
  // ---- prep_x ----
  const int wid = (b - NBLK) * 4 + (threadIdx.x >> 6);
  const int lane = threadIdx.x & 63;
  const int k = lane * 2;
  if (wid >= N_NODES) {  // pad rows: zero xb + aggb
    f16x2 z; z[0] = (f16)0.f; z[1] = (f16)0.f;
    *(f16x2*)&xb[(size_t)wid * 128 + k] = z;
    f16x8 z8;
#pragma unroll
    for (int j = 0; j < 8; ++j) z8[j] = (f16)0.f;
    *(f16x8*)&aggb[(size_t)wid * 512 + lane * 8] = z8;
    return;
  }
  float2 xv = *(const float2*)&x[(size_t)wid * 128 + k];
  f16x2 o; o[0] = (f16)xv.x; o[1] = (f16)xv.y;
  *(f16x2*)&xb[(size_t)wid * 128 + k] = o;
  float4 vs0 = *(const float4*)&V1s[k * 4];
  float4 vs1 = *(const float4*)&V1s[(k + 1) * 4];
  float4 vd0 = *(const float4*)&V1d[k * 4];
  float4 vd1 = *(const float4*)&V1d[(k + 1) * 4];
  float s[4], d[4];
  s[0] = xv.x * vs0.x + xv.y * vs1.x;
  s[1] = xv.x * vs0.y + xv.y * vs1.y;
  s[2] = xv.x * vs0.z + xv.y * vs1.z;
  s[3] = xv.x * vs0.w + xv.y * vs1.w;
  d[0] = xv.x * vd0.x + xv.y * vd1.x;
  d[1] = xv.x * vd0.y + xv.y * vd1.y;
  d[2] = xv.x * vd0.z + xv.y * vd1.z;
  d[3] = xv.x * vd0.w + xv.y * vd1.w;
#pragma unroll
  for (int h = 0; h < 4; ++h) {
#pragma unroll
    for (int off = 32; off; off >>= 1) {
      s[h] += __shfl_xor(s[h], off);
      d[h] += __shfl_xor(d[h], off);
    }
  }
  if (lane == 0) {
    *(float4*)&as1[(size_t)wid * 4] = make_float4(s[0], s[1], s[2], s[3]);
    *(float4*)&ad1[(size_t)wid * 4] = make_float4(d[0], d[1], d[2], d[3]);
  }
}

// 49 blocks: recompute bucket offsets locally (no separate scan kernel),
// finalize rowstart/cursor, scatter degree-sorted order[].
__global__ __launch_bounds__(256) void scatter_addoff2(
    int* __restrict__ pre, const int* __restrict__ bsum,
    int* __restrict__ cursor, const int* __restrict__ deg,
    const int* __restrict__ blkcnt, int* __restrict__ order) {
  __shared__ int lcur[128];
  __shared__ int carry_s;
  __shared__ int boff_s;
  const int t = threadIdx.x;
  const int b = blockIdx.x;
  int x = 0, tot = 0, pre_b = 0;
  if (t < 128) {
    for (int k = 0; k < NBLK; ++k) {
      const int v = blkcnt[t * NBLK + k];
      tot += v;
      if (k < b) pre_b += v;
    }
    x = tot;
#pragma unroll
    for (int off = 1; off < 64; off <<= 1) {
      int y = __shfl_up(x, off);
      if ((t & 63) >= off) x += y;
    }
  }
  if (t == 63) carry_s = x;  // inclusive total of buckets 0..63
  if (t == 255) {
    int s = 0;
    for (int k = 0; k < b; ++k) s += bsum[k];
    boff_s = s;
  }
  __syncthreads();
  if (t < 128) lcur[t] = (x - tot) + (t >= 64 ? carry_s : 0) + pre_b;
  __syncthreads();
  const int base4 = b * 1024 + t * 4;
  const int off = boff_s;
  int4 v = *(const int4*)&pre[base4];
  v.x += off; v.y += off; v.z += off; v.w += off;
  *(int4*)&pre[base4] = v;
  *(int4*)&cursor[base4] = v;
#pragma unroll
  for (int j = 0; j < 4; ++j) {
    const int i = b * 1024 + j * 256 + t;
    if (i < N_NODES) {
      const int bk = min(deg[i], 127);
      const int pos = atomicAdd(&lcur[bk], 1);
      order[pos] = i;
    }
  }
}

// CSR fill + layer-1 edge softmax weights (exp(leaky(as1[s]+ad1[d])), 4 heads)
__global__ void fill_w1(const int* __restrict__ ei, int* __restrict__ cursor,
                        const float* __restrict__ as1, const float* __restrict__ ad1,
                        int* __restrict__ csr, float* __restrict__ wexp1) {
  const int e = blockIdx.x * blockDim.x + threadIdx.x;
  if (e >= TOT_EDGES) return;
  int s, d;
  if (e < N_EDGES) { s = ei[e]; d = ei[N_EDGES + e]; }
  else             { s = d = e - N_EDGES; }
  const int pos = atomicAdd(&cursor[d], 1);
  csr[pos] = s;
  float4 a = *(const float4*)&as1[(size_t)s * 4];
  float4 bz = *(const float4*)&ad1[(size_t)d * 4];
  float4 w;
  w.x = __expf(lrelu(a.x + bz.x));
  w.y = __expf(lrelu(a.y + bz.y));
  w.z = __expf(lrelu(a.z + bz.z));
  w.w = __expf(lrelu(a.w + bz.w));
  *(float4*)&wexp1[(size_t)pos * 4] = w;
}

// ---------------------------------------------------------------------------
// fused MLP: per 128-row stripe, for each head h:
//   C1_h = aggb[:, h*128:+128] @ W1_h ; bias+ELU -> C1s (LDS, f16)
//   a2 partial dots from ELU values (LDS atomics)
//   h2 += C1s @ W2_h   (acc2 held across heads)
// Plain contiguous LDS staging (identity k-perm on both operands).
// ---------------------------------------------------------------------------
#define GLDT 72
#define C1LD 136

__global__ __launch_bounds__(256) void fused_mlp(
    const f16* __restrict__ aggb, const f16* __restrict__ w1t,
    const f16* __restrict__ w2t, const float* __restrict__ bias1,
    const float* __restrict__ V2s, const float* __restrict__ V2d,
    f16* __restrict__ h2b, float* __restrict__ as2, float* __restrict__ ad2) {
  __shared__ __align__(16) f16 As[128 * GLDT];
  __shared__ __align__(16) f16 Bs[128 * GLDT];
  __shared__ __align__(16) f16 C1s[128 * C1LD];
  __shared__ float a2sl[128], a2dl[128];
  const int tid = threadIdx.x;
  const int lane = tid & 63;
  const int g = lane >> 4, r16 = lane & 15;
  const int w = tid >> 6, wr = w >> 1, wc = w & 1;
  const size_t bm = (size_t)blockIdx.x * 128;
  const int row0 = tid >> 2, h0 = tid & 3;

  if (tid < 128) { a2sl[tid] = 0.f; a2dl[tid] = 0.f; }

  f32x4 acc2[4][4] = {};

  for (int h = 0; h < 4; ++h) {
    // ---- stage 1: C1 = aggb_h @ W1_h^T ----
    f32x4 acc1[4][4] = {};
    const f16* Ag = aggb + (size_t)h * 128;
    const f16* Bg = w1t + (size_t)h * 128 * 128;
#pragma unroll
    for (int k0 = 0; k0 < 128; k0 += 64) {
      __syncthreads();
      f16x8 a00 = *(const f16x8*)&Ag[(bm + row0) * 512 + k0 + h0 * 8];
      f16x8 a01 = *(const f16x8*)&Ag[(bm + row0) * 512 + k0 + 32 + h0 * 8];
      f16x8 a10 = *(const f16x8*)&Ag[(bm + row0 + 64) * 512 + k0 + h0 * 8];
      f16x8 a11 = *(const f16x8*)&Ag[(bm + row0 + 64) * 512 + k0 + 32 + h0 * 8];
      f16x8 b00 = *(const f16x8*)&Bg[row0 * 128 + k0 + h0 * 8];
      f16x8 b01 = *(const f16x8*)&Bg[row0 * 128 + k0 + 32 + h0 * 8];
      f16x8 b10 = *(const f16x8*)&Bg[(row0 + 64) * 128 + k0 + h0 * 8];
      f16x8 b11 = *(const f16x8*)&Bg[(row0 + 64) * 128 + k0 + 32 + h0 * 8];
      *(f16x8*)&As[row0 * GLDT + h0 * 8] = a00;
      *(f16x8*)&As[row0 * GLDT + 32 + h0 * 8] = a01;
      *(f16x8*)&As[(row0 + 64) * GLDT + h0 * 8] = a10;
      *(f16x8*)&As[(row0 + 64) * GLDT + 32 + h0 * 8] = a11;
      *(f16x8*)&Bs[row0 * GLDT + h0 * 8] = b00;
      *(f16x8*)&Bs[row0 * GLDT + 32 + h0 * 8] = b01;
      *(f16x8*)&Bs[(row0 + 64) * GLDT + h0 * 8] = b10;
      *(f16x8*)&Bs[(row0 + 64) * GLDT + 32 + h0 * 8] = b11;
      __syncthreads();
#pragma unroll
      for (int ks = 0; ks < 2; ++ks) {
        f16x8 af[4], bf[4];
#pragma unroll
        for (int m = 0; m < 4; ++m)
          af[m] = *(const f16x8*)&As[(wr * 64 + m * 16 + r16) * GLDT + ks * 32 + g * 8];
#pragma unroll
        for (int n = 0; n < 4; ++n)
          bf[n] = *(const f16x8*)&Bs[(wc * 64 + n * 16 + r16) * GLDT + ks * 32 + g * 8];
#pragma unroll
        for (int m = 0; m < 4; ++m)
#pragma unroll
          for (int n = 0; n < 4; ++n)
            acc1[m][n] = __builtin_amdgcn_mfma_f32_16x16x32_f16(af[m], bf[n], acc1[m][n], 0, 0, 0);
      }
    }
    // ---- bias + ELU -> C1s ; a2 partial dots ----
    float bv[4], vsv[4], vdv[4];
#pragma unroll
    for (int n = 0; n < 4; ++n) {
      const int c = h * 128 + wc * 64 + n * 16 + r16;
      bv[n] = bias1[c];
      vsv[n] = V2s[c];
      vdv[n] = V2d[c];
    }
#pragma unroll
    for (int m = 0; m < 4; ++m) {
#pragma unroll
      for (int r = 0; r < 4; ++r) {
        const int rl = wr * 64 + m * 16 + g * 4 + r;
        float sp = 0.f, dp = 0.f;
#pragma unroll
        for (int n = 0; n < 4; ++n) {
          float v = acc1[m][n][r] + bv[n];
          v = v > 0.f ? v : (__expf(v) - 1.f);
          C1s[rl * C1LD + wc * 64 + n * 16 + r16] = (f16)v;
          sp += v * vsv[n];
          dp += v * vdv[n];
        }
        atomicAdd(&a2sl[rl], sp);
        atomicAdd(&a2dl[rl], dp);
      }
    }
    // ---- stage 2: acc2 += C1s @ W2_h^T ----
    const f16* B2g = w2t + (size_t)h * 128;
#pragma unroll
    for (int k0 = 0; k0 < 128; k0 += 64) {
      __syncthreads();
      f16x8 b00 = *(const f16x8*)&B2g[(size_t)row0 * 512 + k0 + h0 * 8];
      f16x8 b01 = *(const f16x8*)&B2g[(size_t)row0 * 512 + k0 + 32 + h0 * 8];
      f16x8 b10 = *(const f16x8*)&B2g[(size_t)(row0 + 64) * 512 + k0 + h0 * 8];
      f16x8 b11 = *(const f16x8*)&B2g[(size_t)(row0 + 64) * 512 + k0 + 32 + h0 * 8];
      *(f16x8*)&Bs[row0 * GLDT + h0 * 8] = b00;
      *(f16x8*)&Bs[row0 * GLDT + 32 + h0 * 8] = b01;
      *(f16x8*)&Bs[(row0 + 64) * GLDT + h0 * 8] = b10;
      *(f16x8*)&Bs[(row0 + 64) * GLDT + 32 + h0 * 8] = b11;
      __syncthreads();
#pragma unroll
      for (int ks = 0; ks < 2; ++ks) {
        f16x8 af[4], bf[4];
#pragma unroll
        for (int m = 0; m < 4; ++m)
          af[m] = *(const f16x8*)&C1s[(wr * 64 + m * 16 + r16) * C1LD + k0 + ks * 32 + g * 8];
#pragma unroll
        for (int n = 0; n < 4; ++n)
          bf[n] = *(const f16x8*)&Bs[(wc * 64 + n * 16 + r16) * GLDT + ks * 32 + g * 8];
#pragma unroll
        for (int m = 0; m < 4; ++m)
#pragma unroll
          for (int n = 0; n < 4; ++n)
            acc2[m][n] = __builtin_amdgcn_mfma_f32_16x16x32_f16(af[m], bf[n], acc2[m][n], 0, 0, 0);
      }
    }
  }
  __syncthreads();
  if (tid < 128) {
    as2[bm + tid] = a2sl[tid];
    ad2[bm + tid] = a2dl[tid];
  }
#pragma unroll
  for (int m = 0; m < 4; ++m)
#pragma unroll
    for (int n = 0; n < 4; ++n) {
      const size_t row = bm + wr * 64 + m * 16 + g * 4;
      const int col = wc * 64 + n * 16 + r16;
#pragma unroll
      for (int r = 0; r < 4; ++r)
        h2b[(row + r) * 128 + col] = (f16)acc2[m][n][r];
    }
}

// ---------------------------------------------------------------------------
// layer-1 aggregation in input space, 4 nodes/wave, reversed degree order
// (heavy blocks first), unmasked main loop to mindeg + masked tail.
// ---------------------------------------------------------------------------
__global__ __launch_bounds__(256) void aggregate1x(
    const f16* __restrict__ xsrc, const float* __restrict__ wexp,
    const int* __restrict__ rowstart, const int* __restrict__ csr,
    const int* __restrict__ order, f16* __restrict__ aggb) {
  const int wave = (blockIdx.x * blockDim.x + threadIdx.x) >> 6;
  const int lane = threadIdx.x & 63;
  const int g16 = lane >> 4, l16 = lane & 15;
  const int node = order[N_NODES - 1 - (wave * 4 + g16)];
  const int col0 = l16 * 8;
  const int rs = rowstart[node];
  const int re = rowstart[node + 1];
  const int deg = re - rs;

  int maxdeg = deg, mindeg = deg;
  maxdeg = max(maxdeg, __shfl_xor(maxdeg, 16));
  maxdeg = max(maxdeg, __shfl_xor(maxdeg, 32));
  mindeg = min(mindeg, __shfl_xor(mindeg, 16));
  mindeg = min(mindeg, __shfl_xor(mindeg, 32));

  constexpr int D = 4;
  int sreg[D];
  float4 wreg[D];
  f16x8 hreg[D];
#pragma unroll
  for (int p = 0; p < D; ++p) {
    const int k = rs + p;
    const int kc = (k < re) ? k : (re - 1);
    wreg[p] = *(const float4*)&wexp[(size_t)kc * 4];
    const int s = csr[kc];
    hreg[p] = *(const f16x8*)&xsrc[(size_t)s * 128 + col0];
    const int k2 = rs + D + p;
    sreg[p] = csr[(k2 < re) ? k2 : (re - 1)];
  }

  float acc0[8] = {}, acc1[8] = {}, acc2[8] = {}, acc3[8] = {};
  float Z0 = 0.f, Z1 = 0.f, Z2 = 0.f, Z3 = 0.f;

  int base = 0;
  for (; base + D <= mindeg; base += D) {  // unmasked main loop
#pragma unroll
    for (int p = 0; p < D; ++p) {
      const int i = base + p;
      const float4 wv = wreg[p];
      const f16x8 h = hreg[p];
      const int nk = rs + i + D;
      if (nk < re) {
        wreg[p] = *(const float4*)&wexp[(size_t)nk * 4];
        const int s = sreg[p];
        hreg[p] = *(const f16x8*)&xsrc[(size_t)s * 128 + col0];
      }
      const int nk2 = rs + i + 2 * D;
      if (nk2 < re) sreg[p] = csr[nk2];
      Z0 += wv.x; Z1 += wv.y; Z2 += wv.z; Z3 += wv.w;
#pragma unroll
      for (int j = 0; j < 8; ++j) {
        const float hv = (float)h[j];
        acc0[j] += wv.x * hv;
        acc1[j] += wv.y * hv;
        acc2[j] += wv.z * hv;
        acc3[j] += wv.w * hv;
      }
    }
  }
  for (; base < maxdeg; base += D) {  // masked tail
#pragma unroll
    for (int p = 0; p < D; ++p) {
      const int i = base + p;
      const bool act = i < deg;
      const float4 wv = wreg[p];
      const float w0 = act ? wv.x : 0.f;
      const float w1 = act ? wv.y : 0.f;
      const float w2 = act ? wv.z : 0.f;
      const float w3 = act ? wv.w : 0.f;
      const f16x8 h = hreg[p];
      const int nk = rs + i + D;
      if (nk < re) {
        wreg[p] = *(const float4*)&wexp[(size_t)nk * 4];
        const int s = sreg[p];
        hreg[p] = *(const f16x8*)&xsrc[(size_t)s * 128 + col0];
      }
      const int nk2 = rs + i + 2 * D;
      if (nk2 < re) sreg[p] = csr[nk2];
      Z0 += w0; Z1 += w1; Z2 += w2; Z3 += w3;
#pragma unroll
      for (int j = 0; j < 8; ++j) {
        const float hv = (float)h[j];
        acc0[j] += w0 * hv;
        acc1[j] += w1 * hv;
        acc2[j] += w2 * hv;
        acc3[j] += w3 * hv;
      }
    }
  }

  const float i0 = 1.f / (Z0 + 1e-16f);
  const float i1 = 1.f / (Z1 + 1e-16f);
  const float i2 = 1.f / (Z2 + 1e-16f);
  const float i3 = 1.f / (Z3 + 1e-16f);
  f16* orow = aggb + (size_t)node * 512 + col0;
  f16x8 o0, o1, o2, o3;
#pragma unroll
  for (int j = 0; j < 8; ++j) {
    o0[j] = (f16)(acc0[j] * i0);
    o1[j] = (f16)(acc1[j] * i1);
    o2[j] = (f16)(acc2[j] * i2);
    o3[j] = (f16)(acc3[j] * i3);
  }
  *(f16x8*)&orow[0]   = o0;
  *(f16x8*)&orow[128] = o1;
  *(f16x8*)&orow[256] = o2;
  *(f16x8*)&orow[384] = o3;
}

// ---------------------------------------------------------------------------
// layer-2 aggregation, 4 nodes/wave, reversed order, inline edge weights,
// fused bias/ELU/L2-normalize.
// ---------------------------------------------------------------------------
__global__ __launch_bounds__(256) void aggregate2(
    const f16* __restrict__ hsrc, const float* __restrict__ as2,
    const float* __restrict__ ad2, const int* __restrict__ rowstart,
    const int* __restrict__ csr, const int* __restrict__ order,
    const float* __restrict__ bias, float* __restrict__ out) {
  const int wave = (blockIdx.x * blockDim.x + threadIdx.x) >> 6;
  const int lane = threadIdx.x & 63;
  const int g16 = lane >> 4, l16 = lane & 15;
  const int node = order[N_NODES - 1 - (wave * 4 + g16)];
  const int col0 = l16 * 8;
  const int rs = rowstart[node];
  const int re = rowstart[node + 1];
  const int deg = re - rs;
  const float ad = ad2[node];

  int maxdeg = deg, mindeg = deg;
  maxdeg = max(maxdeg, __shfl_xor(maxdeg, 16));
  maxdeg = max(maxdeg, __shfl_xor(maxdeg, 32));
  mindeg = min(mindeg, __shfl_xor(mindeg, 16));
  mindeg = min(mindeg, __shfl_xor(mindeg, 32));

  constexpr int D = 6;
  int sreg[D];
  float areg[D];
  f16x8 hreg[D];
#pragma unroll
  for (int p = 0; p < D; ++p) {
    const int k = rs + p;
    const int kc = (k < re) ? k : (re - 1);
    const int s = csr[kc];
    areg[p] = as2[s];
    hreg[p] = *(const f16x8*)&hsrc[(size_t)s * 128 + col0];
    const int k2 = rs + D + p;
    sreg[p] = csr[(k2 < re) ? k2 : (re - 1)];
  }

  float acc[8] = {};
  float Z = 0.f;
  int base = 0;
  for (; base + D <= mindeg; base += D) {  // unmasked main loop
#pragma unroll
    for (int p = 0; p < D; ++p) {
      const int i = base + p;
      const float w = __expf(lrelu(areg[p] + ad));
      const f16x8 h = hreg[p];
      const int nk = rs + i + D;
      if (nk < re) {
        const int s = sreg[p];
        areg[p] = as2[s];
        hreg[p] = *(const f16x8*)&hsrc[(size_t)s * 128 + col0];
      }
      const int nk2 = rs + i + 2 * D;
      if (nk2 < re) sreg[p] = csr[nk2];
      Z += w;
#pragma unroll
      for (int j = 0; j < 8; ++j) acc[j] += w * (float)h[j];
    }
  }
  for (; base < maxdeg; base += D) {  // masked tail
#pragma unroll
    for (int p = 0; p < D; ++p) {
      const int i = base + p;
      const bool act = i < deg;
      const float w = act ? __expf(lrelu(areg[p] + ad)) : 0.f;
      const f16x8 h = hreg[p];
      const int nk = rs + i + D;
      if (nk < re) {
        const int s = sreg[p];
        areg[p] = as2[s];
        hreg[p] = *(const f16x8*)&hsrc[(size_t)s * 128 + col0];
      }
      const int nk2 = rs + i + 2 * D;
      if (nk2 < re) sreg[p] = csr[nk2];
      Z += w;
#pragma unroll
      for (int j = 0; j < 8; ++j) acc[j] += w * (float)h[j];
    }
  }
  const float inv = 1.f / (Z + 1e-16f);

  float4 ba = *(const float4*)&bias[col0];
  float4 bb = *(const float4*)&bias[col0 + 4];
  const float bv[8] = {ba.x, ba.y, ba.z, ba.w, bb.x, bb.y, bb.z, bb.w};
  float v[8];
  float ss = 0.f;
#pragma unroll
  for (int j = 0; j < 8; ++j) {
    float t = acc[j] * inv + bv[j];
    t = t > 0.f ? t : (__expf(t) - 1.f);
    v[j] = t;
    ss += t * t;
  }
  ss += __shfl_xor(ss, 1);
  ss += __shfl_xor(ss, 2);
  ss += __shfl_xor(ss, 4);
  ss += __shfl_xor(ss, 8);
  const float invn = 1.f / fmaxf(sqrtf(ss), 1e-12f);
  float* orow = out + (size_t)node * 128 + col0;
  float4 oa = make_float4(v[0] * invn, v[1] * invn, v[2] * invn, v[3] * invn);
  float4 ob = make_float4(v[4] * invn, v[5] * invn, v[6] * invn, v[7] * invn);
  *(float4*)&orow[0] = oa;
  *(float4*)&orow[4] = ob;
}

// ---------------------------------------------------------------------------
extern "C" void kernel_launch(void* const* d_in, const int* in_sizes, int n_in,
                              void* d_out, int out_size, void* d_ws, size_t ws_size,
                              hipStream_t stream) {
  const float* x        = (const float*)d_in[0];
  const int*   ei       = (const int*)d_in[1];
  const float* W1       = (const float*)d_in[2];
  const float* att_src1 = (const float*)d_in[3];
  const float* att_dst1 = (const float*)d_in[4];
  const float* bias1    = (const float*)d_in[5];
  const float* W2       = (const float*)d_in[6];
  const float* att_src2 = (const float*)d_in[7];
  const float* att_dst2 = (const float*)d_in[8];
  const float* bias2    = (const float*)d_in[9];
  float* out = (float*)d_out;

  char* ws = (char*)d_ws;
  size_t off = 0;
  auto alloc = [&](size_t bytes) {
    char* p = ws + off;
    off = (off + bytes + 255) & ~(size_t)255;
    return p;
  };
  f16* xb    = (f16*)alloc(sizeof(f16) * (size_t)M_PAD * 128);
  f16* w1t   = (f16*)alloc(sizeof(f16) * 512 * 128);
  f16* w2t   = (f16*)alloc(sizeof(f16) * 128 * 512);
  f16* aggb  = (f16*)alloc(sizeof(f16) * (size_t)M_PAD * 512);
  f16* h2b   = (f16*)alloc(sizeof(f16) * (size_t)M_PAD * 128);
  float* V1s = (float*)alloc(sizeof(float) * 512);
  float* V1d = (float*)alloc(sizeof(float) * 512);
  float* V2s = (float*)alloc(sizeof(float) * 512);
  float* V2d = (float*)alloc(sizeof(float) * 512);
  float* as1 = (float*)alloc(sizeof(float) * N_NODES * 4);
  float* ad1 = (float*)alloc(sizeof(float) * N_NODES * 4);
  float* as2 = (float*)alloc(sizeof(float) * M_PAD);
  float* ad2 = (float*)alloc(sizeof(float) * M_PAD);
  float* wexp1 = (float*)alloc(sizeof(float) * (size_t)TOT_EDGES * 4);
  int* rowstart = (int*)alloc(sizeof(int) * (SCAN_PAD + 4));
  int* deg      = (int*)alloc(sizeof(int) * SCAN_PAD);
  int* cursor   = (int*)alloc(sizeof(int) * SCAN_PAD);
  int* bsum     = (int*)alloc(sizeof(int) * 64);
  int* blkcnt   = (int*)alloc(sizeof(int) * 128 * NBLK);
  int* order    = (int*)alloc(sizeof(int) * N_NODES);
  int* csr      = (int*)alloc(sizeof(int) * TOT_EDGES);

  const int agrid = (N_NODES / 4) * 64 / 256;  // 3125 blocks, 4 nodes/wave

  // 1: zero degree array
  zero_int<<<(SCAN_PAD + 255) / 256, 256, 0, stream>>>(deg, SCAN_PAD);
  // 2: degree count + weight/projection prep (disjoint block ranges)
  count_weights<<<CNT_BLKS + 768, 256, 0, stream>>>(
      ei, deg, W1, W2, att_src1, att_dst1, att_src2, att_dst2,
      w1t, w2t, V1s, V1d, V2s, V2d);
  // 3: degree histogram + block scan  |  prep_x (xb, a1, aggb pad)
  histscan_prepx<<<NBLK + M_PAD / 4, 256, 0, stream>>>(
      deg, rowstart, bsum, blkcnt, x, xb, V1s, V1d, as1, ad1, aggb);
  // 4: offsets (recomputed in-block) + rowstart/cursor finalize + order scatter
  scatter_addoff2<<<NBLK, 256, 0, stream>>>(rowstart, bsum, cursor, deg, blkcnt, order);
  // 5: CSR fill + layer-1 edge weights
  fill_w1<<<CNT_BLKS, 256, 0, stream>>>(ei, cursor, as1, ad1, csr, wexp1);
  // 6: layer-1 aggregation (input space, heavy-first)
  aggregate1x<<<agrid, 256, 0, stream>>>(xb, wexp1, rowstart, csr, order, aggb);
  // 7: fused MLP: head-GEMMs + bias/ELU + a2 dots + layer-2 GEMM
  fused_mlp<<<M_PAD / 128, 256, 0, stream>>>(
      aggb, w1t, w2t, bias1, V2s, V2d, h2b, as2, ad2);
  // 8: layer-2 aggregation + bias/ELU/L2-normalize (heavy-first)
  aggregate2<<<agrid, 256, 0, stream>>>(h2b, as2, ad2, rowstart, csr, order, bias2, out);
}

// Round 12
// 190.646 us; speedup vs baseline: 1.4618x; 1.4618x over previous
//
#include <hip/hip_runtime.h>
#include <cstddef>

#define N_NODES 50000
#define N_EDGES 400000
#define TOT_EDGES (N_EDGES + N_NODES)
#define M_PAD 50048    // 391 * 128  (GEMM row padding)
#define SCAN_PAD 50176 // 49 * 1024  (scan padding)
#define NBLK 49
#define CNT_BLKS 1758  // ceil(TOT_EDGES/256)

typedef _Float16 f16;
typedef __attribute__((ext_vector_type(8))) _Float16 f16x8;
typedef __attribute__((ext_vector_type(4))) _Float16 f16x4;
typedef __attribute__((ext_vector_type(2))) _Float16 f16x2;
typedef __attribute__((ext_vector_type(4))) float f32x4;

__device__ __forceinline__ float lrelu(float e) { return e > 0.f ? e : 0.2f * e; }

// ---------------------------------------------------------------------------
__global__ void zero_int(int* __restrict__ p, int n) {
  int i = blockIdx.x * blockDim.x + threadIdx.x;
  if (i < n) p[i] = 0;
}

// blocks [0,CNT_BLKS): degree count; [CNT_BLKS, CNT_BLKS+768): weight prep
__global__ __launch_bounds__(256) void count_weights(
    const int* __restrict__ ei, int* __restrict__ deg,
    const float* __restrict__ W1, const float* __restrict__ W2,
    const float* __restrict__ att_s1, const float* __restrict__ att_d1,
    const float* __restrict__ att_s2, const float* __restrict__ att_d2,
    f16* __restrict__ w1t, f16* __restrict__ w2t,
    float* __restrict__ V1s, float* __restrict__ V1d,
    float* __restrict__ V2s, float* __restrict__ V2d) {
  const int b = blockIdx.x;
  if (b < CNT_BLKS) {
    const int e = b * 256 + threadIdx.x;
    if (e >= TOT_EDGES) return;
    const int dst = (e < N_EDGES) ? ei[N_EDGES + e] : (e - N_EDGES);
    atomicAdd(&deg[dst], 1);
    return;
  }
  const int bb = b - CNT_BLKS;
  if (bb < 256) {  // W1[128][512] -> w1t[512][128]
    const int idx = bb * 256 + threadIdx.x;
    const int cc = idx >> 7, rr = idx & 127;
    w1t[idx] = (f16)W1[(size_t)rr * 512 + cc];
  } else if (bb < 512) {  // W2[512][128] -> w2t[128][512]
    const int idx = (bb - 256) * 256 + threadIdx.x;
    const int cc = idx >> 9, rr = idx & 511;
    w2t[idx] = (f16)W2[(size_t)rr * 128 + cc];
  } else if (bb < 640) {  // V1
    const int wid = (bb - 512) * 4 + (threadIdx.x >> 6);
    const int lane = threadIdx.x & 63;
    const int k = wid >> 2, h = wid & 3;
    const float* wrow = W1 + (size_t)k * 512 + h * 128;
    float2 wv = *(const float2*)&wrow[lane * 2];
    float2 sv = *(const float2*)&att_s1[h * 128 + lane * 2];
    float2 dv = *(const float2*)&att_d1[h * 128 + lane * 2];
    float ps = wv.x * sv.x + wv.y * sv.y;
    float pd = wv.x * dv.x + wv.y * dv.y;
#pragma unroll
    for (int off = 32; off; off >>= 1) {
      ps += __shfl_xor(ps, off);
      pd += __shfl_xor(pd, off);
    }
    if (lane == 0) { V1s[k * 4 + h] = ps; V1d[k * 4 + h] = pd; }
  } else {  // V2
    const int wid = (bb - 640) * 4 + (threadIdx.x >> 6);
    const int lane = threadIdx.x & 63;
    const float* wrow = W2 + (size_t)wid * 128;
    float2 wv = *(const float2*)&wrow[lane * 2];
    float2 sv = *(const float2*)&att_s2[lane * 2];
    float2 dv = *(const float2*)&att_d2[lane * 2];
    float ps = wv.x * sv.x + wv.y * sv.y;
    float pd = wv.x * dv.x + wv.y * dv.y;
#pragma unroll
    for (int off = 32; off; off >>= 1) {
      ps += __shfl_xor(ps, off);
      pd += __shfl_xor(pd, off);
    }
    if (lane == 0) { V2s[wid] = ps; V2d[wid] = pd; }
  }
}

// blocks [0,NBLK): LDS degree histogram + block scan of deg (bsum = RAW totals);
// blocks [NBLK, NBLK+12512): prep_x (xb cvt, a1 = x.V1, aggb pad zero)
__global__ __launch_bounds__(256) void histscan_prepx(
    const int* __restrict__ deg, int* __restrict__ pre, int* __restrict__ bsum,
    int* __restrict__ blkcnt,
    const float* __restrict__ x, f16* __restrict__ xb,
    const float* __restrict__ V1s, const float* __restrict__ V1d,
    float* __restrict__ as1, float* __restrict__ ad1, f16* __restrict__ aggb) {
  __shared__ int wsum[4];
  __shared__ int lh[128];
  const int b = blockIdx.x;
  if (b < NBLK) {
    const int t = threadIdx.x, lane = t & 63, w = t >> 6;
    if (t < 128) lh[t] = 0;
    __syncthreads();
    const int base = b * 1024 + t * 4;
    int4 v = *(const int4*)&deg[base];
    if (base + 0 < N_NODES) atomicAdd(&lh[min(v.x, 127)], 1);
    if (base + 1 < N_NODES) atomicAdd(&lh[min(v.y, 127)], 1);
    if (base + 2 < N_NODES) atomicAdd(&lh[min(v.z, 127)], 1);
    if (base + 3 < N_NODES) atomicAdd(&lh[min(v.w, 127)], 1);
    const int s = v.x + v.y + v.z + v.w;
    int xx = s;
#pragma unroll
    for (int off = 1; off < 64; off <<= 1) {
      int y = __shfl_up(xx, off);
      if (lane >= off) xx += y;
    }
    if (lane == 63) wsum[w] = xx;
    __syncthreads();
    int woff = 0;
    for (int j = 0; j < w; ++j) woff += wsum[j];
    const int ex = xx - s + woff;
    pre[base + 0] = ex;
    pre[base + 1] = ex + v.x;
    pre[base + 2] = ex + v.x + v.y;
    pre[base + 3] = ex + v.x + v.y + v.z;
    if (t == 255) bsum[b] = ex + s;  // raw block total
    if (t < 128) blkcnt[t * NBLK + b] = lh[t];
    return;
  }
  // ---- prep_x ----
  const int wid = (b - NBLK) * 4 + (threadIdx.x >> 6);
  const int lane = threadIdx.x & 63;
  const int k = lane * 2;
  if (wid >= N_NODES) {  // pad rows: zero xb + aggb
    f16x2 z; z[0] = (f16)0.f; z[1] = (f16)0.f;
    *(f16x2*)&xb[(size_t)wid * 128 + k] = z;
    f16x8 z8;
#pragma unroll
    for (int j = 0; j < 8; ++j) z8[j] = (f16)0.f;
    *(f16x8*)&aggb[(size_t)wid * 512 + lane * 8] = z8;
    return;
  }
  float2 xv = *(const float2*)&x[(size_t)wid * 128 + k];
  f16x2 o; o[0] = (f16)xv.x; o[1] = (f16)xv.y;
  *(f16x2*)&xb[(size_t)wid * 128 + k] = o;
  float4 vs0 = *(const float4*)&V1s[k * 4];
  float4 vs1 = *(const float4*)&V1s[(k + 1) * 4];
  float4 vd0 = *(const float4*)&V1d[k * 4];
  float4 vd1 = *(const float4*)&V1d[(k + 1) * 4];
  float s[4], d[4];
  s[0] = xv.x * vs0.x + xv.y * vs1.x;
  s[1] = xv.x * vs0.y + xv.y * vs1.y;
  s[2] = xv.x * vs0.z + xv.y * vs1.z;
  s[3] = xv.x * vs0.w + xv.y * vs1.w;
  d[0] = xv.x * vd0.x + xv.y * vd1.x;
  d[1] = xv.x * vd0.y + xv.y * vd1.y;
  d[2] = xv.x * vd0.z + xv.y * vd1.z;
  d[3] = xv.x * vd0.w + xv.y * vd1.w;
#pragma unroll
  for (int h = 0; h < 4; ++h) {
#pragma unroll
    for (int off = 32; off; off >>= 1) {
      s[h] += __shfl_xor(s[h], off);
      d[h] += __shfl_xor(d[h], off);
    }
  }
  if (lane == 0) {
    *(float4*)&as1[(size_t)wid * 4] = make_float4(s[0], s[1], s[2], s[3]);
    *(float4*)&ad1[(size_t)wid * 4] = make_float4(d[0], d[1], d[2], d[3]);
  }
}

// 49 blocks: recompute bucket offsets locally (no separate scan kernel),
// finalize rowstart/cursor, scatter degree-sorted order[].
__global__ __launch_bounds__(256) void scatter_addoff2(
    int* __restrict__ pre, const int* __restrict__ bsum,
    int* __restrict__ cursor, const int* __restrict__ deg,
    const int* __restrict__ blkcnt, int* __restrict__ order) {
  __shared__ int lcur[128];
  __shared__ int carry_s;
  __shared__ int boff_s;
  const int t = threadIdx.x;
  const int b = blockIdx.x;
  int x = 0, tot = 0, pre_b = 0;
  if (t < 128) {
    for (int k = 0; k < NBLK; ++k) {
      const int v = blkcnt[t * NBLK + k];
      tot += v;
      if (k < b) pre_b += v;
    }
    x = tot;
#pragma unroll
    for (int off = 1; off < 64; off <<= 1) {
      int y = __shfl_up(x, off);
      if ((t & 63) >= off) x += y;
    }
  }
  if (t == 63) carry_s = x;  // inclusive total of buckets 0..63
  if (t == 255) {
    int s = 0;
    for (int k = 0; k < b; ++k) s += bsum[k];
    boff_s = s;
  }
  __syncthreads();
  if (t < 128) lcur[t] = (x - tot) + (t >= 64 ? carry_s : 0) + pre_b;
  __syncthreads();
  const int base4 = b * 1024 + t * 4;
  const int off = boff_s;
  int4 v = *(const int4*)&pre[base4];
  v.x += off; v.y += off; v.z += off; v.w += off;
  *(int4*)&pre[base4] = v;
  *(int4*)&cursor[base4] = v;
#pragma unroll
  for (int j = 0; j < 4; ++j) {
    const int i = b * 1024 + j * 256 + t;
    if (i < N_NODES) {
      const int bk = min(deg[i], 127);
      const int pos = atomicAdd(&lcur[bk], 1);
      order[pos] = i;
    }
  }
}

// CSR fill + layer-1 edge softmax weights (exp(leaky(as1[s]+ad1[d])), 4 heads)
__global__ void fill_w1(const int* __restrict__ ei, int* __restrict__ cursor,
                        const float* __restrict__ as1, const float* __restrict__ ad1,
                        int* __restrict__ csr, float* __restrict__ wexp1) {
  const int e = blockIdx.x * blockDim.x + threadIdx.x;
  if (e >= TOT_EDGES) return;
  int s, d;
  if (e < N_EDGES) { s = ei[e]; d = ei[N_EDGES + e]; }
  else             { s = d = e - N_EDGES; }
  const int pos = atomicAdd(&cursor[d], 1);
  csr[pos] = s;
  float4 a = *(const float4*)&as1[(size_t)s * 4];
  float4 bz = *(const float4*)&ad1[(size_t)d * 4];
  float4 w;
  w.x = __expf(lrelu(a.x + bz.x));
  w.y = __expf(lrelu(a.y + bz.y));
  w.z = __expf(lrelu(a.z + bz.z));
  w.w = __expf(lrelu(a.w + bz.w));
  *(float4*)&wexp1[(size_t)pos * 4] = w;
}

// ---------------------------------------------------------------------------
// MFMA GEMM, BK=64 (2 barriers per 64-wide K-step, 32 MFMAs between).
// FUSE_A2 computes as2/ad2 = A-row . V2{s,d} during staging.
// ---------------------------------------------------------------------------
template <int K, bool PER_HEAD, bool FUSE_A2>
__global__ __launch_bounds__(256) void gemm_bt(const f16* __restrict__ A, int lda,
                                               const f16* __restrict__ Bt, int ldb,
                                               f16* __restrict__ C, int ldc,
                                               const float* __restrict__ bias,
                                               const float* __restrict__ V2s,
                                               const float* __restrict__ V2d,
                                               float* __restrict__ as2,
                                               float* __restrict__ ad2) {
  if constexpr (PER_HEAD) {
    const int hh = blockIdx.y;
    A += (size_t)hh * 128;
    Bt += (size_t)hh * 128 * 128;
    C += (size_t)hh * 128;
    bias += hh * 128;
  }
  constexpr int LDT = 72;  // 64 + 8 pad elems; 144B rows (16B-aligned)
  __shared__ __align__(16) f16 As[128 * LDT];
  __shared__ __align__(16) f16 Bs[128 * LDT];
  const int tid = threadIdx.x;
  const int lane = tid & 63;
  const int g = lane >> 4, r16 = lane & 15;
  const int w = tid >> 6, wr = w >> 1, wc = w & 1;
  const long bm = (long)blockIdx.x * 128;

  const int row0 = tid >> 2, h0 = tid & 3;
  const int p1 = (h0 & 1) * 16 + (h0 >> 1) * 4;
  const size_t ga0 = (size_t)(bm + row0) * lda + h0 * 8;
  const size_t ga1 = (size_t)(bm + row0 + 64) * lda + h0 * 8;
  const size_t gb0 = (size_t)row0 * ldb + h0 * 8;
  const size_t gb1 = (size_t)(row0 + 64) * ldb + h0 * 8;
  const int la0 = row0 * LDT + p1, la1 = (row0 + 64) * LDT + p1;

  f32x4 acc[4][4] = {};
  float s2a = 0.f, d2a = 0.f, s2b = 0.f, d2b = 0.f;

  for (int k0 = 0; k0 < K; k0 += 64) {
    __syncthreads();
    f16x8 a0k0 = *(const f16x8*)&A[ga0 + k0];
    f16x8 a0k1 = *(const f16x8*)&A[ga0 + k0 + 32];
    f16x8 a1k0 = *(const f16x8*)&A[ga1 + k0];
    f16x8 a1k1 = *(const f16x8*)&A[ga1 + k0 + 32];
    f16x8 b0k0 = *(const f16x8*)&Bt[gb0 + k0];
    f16x8 b0k1 = *(const f16x8*)&Bt[gb0 + k0 + 32];
    f16x8 b1k0 = *(const f16x8*)&Bt[gb1 + k0];
    f16x8 b1k1 = *(const f16x8*)&Bt[gb1 + k0 + 32];
    if constexpr (FUSE_A2) {
#pragma unroll
      for (int c = 0; c < 2; ++c) {
        const int kc = k0 + c * 32 + h0 * 8;
        const f16x8 va = c ? a0k1 : a0k0;
        const f16x8 vb = c ? a1k1 : a1k0;
        float4 vsa = *(const float4*)&V2s[kc];
        float4 vsb = *(const float4*)&V2s[kc + 4];
        float4 vda = *(const float4*)&V2d[kc];
        float4 vdb = *(const float4*)&V2d[kc + 4];
        const float vs[8] = {vsa.x, vsa.y, vsa.z, vsa.w, vsb.x, vsb.y, vsb.z, vsb.w};
        const float vd[8] = {vda.x, vda.y, vda.z, vda.w, vdb.x, vdb.y, vdb.z, vdb.w};
#pragma unroll
        for (int j = 0; j < 8; ++j) {
          s2a += (float)va[j] * vs[j];
          d2a += (float)va[j] * vd[j];
          s2b += (float)vb[j] * vs[j];
          d2b += (float)vb[j] * vd[j];
        }
      }
    }
    *(f16x4*)&As[la0]      = __builtin_shufflevector(a0k0, a0k0, 0, 1, 2, 3);
    *(f16x4*)&As[la0 + 8]  = __builtin_shufflevector(a0k0, a0k0, 4, 5, 6, 7);
    *(f16x4*)&As[la0 + 32] = __builtin_shufflevector(a0k1, a0k1, 0, 1, 2, 3);
    *(f16x4*)&As[la0 + 40] = __builtin_shufflevector(a0k1, a0k1, 4, 5, 6, 7);
    *(f16x4*)&As[la1]      = __builtin_shufflevector(a1k0, a1k0, 0, 1, 2, 3);
    *(f16x4*)&As[la1 + 8]  = __builtin_shufflevector(a1k0, a1k0, 4, 5, 6, 7);
    *(f16x4*)&As[la1 + 32] = __builtin_shufflevector(a1k1, a1k1, 0, 1, 2, 3);
    *(f16x4*)&As[la1 + 40] = __builtin_shufflevector(a1k1, a1k1, 4, 5, 6, 7);
    *(f16x4*)&Bs[la0]      = __builtin_shufflevector(b0k0, b0k0, 0, 1, 2, 3);
    *(f16x4*)&Bs[la0 + 8]  = __builtin_shufflevector(b0k0, b0k0, 4, 5, 6, 7);
    *(f16x4*)&Bs[la0 + 32] = __builtin_shufflevector(b0k1, b0k1, 0, 1, 2, 3);
    *(f16x4*)&Bs[la0 + 40] = __builtin_shufflevector(b0k1, b0k1, 4, 5, 6, 7);
    *(f16x4*)&Bs[la1]      = __builtin_shufflevector(b1k0, b1k0, 0, 1, 2, 3);
    *(f16x4*)&Bs[la1 + 8]  = __builtin_shufflevector(b1k0, b1k0, 4, 5, 6, 7);
    *(f16x4*)&Bs[la1 + 32] = __builtin_shufflevector(b1k1, b1k1, 0, 1, 2, 3);
    *(f16x4*)&Bs[la1 + 40] = __builtin_shufflevector(b1k1, b1k1, 4, 5, 6, 7);
    __syncthreads();
#pragma unroll
    for (int ks = 0; ks < 2; ++ks) {
      f16x8 af[4], bfv[4];
#pragma unroll
      for (int m = 0; m < 4; ++m)
        af[m] = *(const f16x8*)&As[(wr * 64 + m * 16 + r16) * LDT + ks * 32 + g * 8];
#pragma unroll
      for (int n = 0; n < 4; ++n)
        bfv[n] = *(const f16x8*)&Bs[(wc * 64 + n * 16 + r16) * LDT + ks * 32 + g * 8];
#pragma unroll
      for (int m = 0; m < 4; ++m)
#pragma unroll
        for (int n = 0; n < 4; ++n)
          acc[m][n] = __builtin_amdgcn_mfma_f32_16x16x32_f16(af[m], bfv[n], acc[m][n], 0, 0, 0);
    }
  }

  if constexpr (FUSE_A2) {
    s2a += __shfl_xor(s2a, 1); s2a += __shfl_xor(s2a, 2);
    d2a += __shfl_xor(d2a, 1); d2a += __shfl_xor(d2a, 2);
    s2b += __shfl_xor(s2b, 1); s2b += __shfl_xor(s2b, 2);
    d2b += __shfl_xor(d2b, 1); d2b += __shfl_xor(d2b, 2);
    if ((tid & 3) == 0) {
      const long r0 = bm + row0;
      as2[r0] = s2a; ad2[r0] = d2a;
      as2[r0 + 64] = s2b; ad2[r0 + 64] = d2b;
    }
  }

  // C/D layout: col = lane&15, row = 4*(lane>>4) + reg
#pragma unroll
  for (int m = 0; m < 4; ++m) {
#pragma unroll
    for (int n = 0; n < 4; ++n) {
      const long row = bm + wr * 64 + m * 16 + g * 4;
      const int col = wc * 64 + n * 16 + r16;
      float bv = 0.f;
      if constexpr (PER_HEAD) bv = bias[col];
#pragma unroll
      for (int r = 0; r < 4; ++r) {
        float v = acc[m][n][r];
        if constexpr (PER_HEAD) {
          v += bv;
          v = v > 0.f ? v : (__expf(v) - 1.f);
        }
        C[(size_t)(row + r) * ldc + col] = (f16)v;
      }
    }
  }
}

// ---------------------------------------------------------------------------
// layer-1 aggregation in input space, 4 nodes/wave, reversed degree order
// (heavy blocks first), unmasked main loop to mindeg + masked tail.
// ---------------------------------------------------------------------------
__global__ __launch_bounds__(256) void aggregate1x(
    const f16* __restrict__ xsrc, const float* __restrict__ wexp,
    const int* __restrict__ rowstart, const int* __restrict__ csr,
    const int* __restrict__ order, f16* __restrict__ aggb) {
  const int wave = (blockIdx.x * blockDim.x + threadIdx.x) >> 6;
  const int lane = threadIdx.x & 63;
  const int g16 = lane >> 4, l16 = lane & 15;
  const int node = order[N_NODES - 1 - (wave * 4 + g16)];
  const int col0 = l16 * 8;
  const int rs = rowstart[node];
  const int re = rowstart[node + 1];
  const int deg = re - rs;

  int maxdeg = deg, mindeg = deg;
  maxdeg = max(maxdeg, __shfl_xor(maxdeg, 16));
  maxdeg = max(maxdeg, __shfl_xor(maxdeg, 32));
  mindeg = min(mindeg, __shfl_xor(mindeg, 16));
  mindeg = min(mindeg, __shfl_xor(mindeg, 32));

  constexpr int D = 4;
  int sreg[D];
  float4 wreg[D];
  f16x8 hreg[D];
#pragma unroll
  for (int p = 0; p < D; ++p) {
    const int k = rs + p;
    const int kc = (k < re) ? k : (re - 1);
    wreg[p] = *(const float4*)&wexp[(size_t)kc * 4];
    const int s = csr[kc];
    hreg[p] = *(const f16x8*)&xsrc[(size_t)s * 128 + col0];
    const int k2 = rs + D + p;
    sreg[p] = csr[(k2 < re) ? k2 : (re - 1)];
  }

  float acc0[8] = {}, acc1[8] = {}, acc2[8] = {}, acc3[8] = {};
  float Z0 = 0.f, Z1 = 0.f, Z2 = 0.f, Z3 = 0.f;

  int base = 0;
  for (; base + D <= mindeg; base += D) {  // unmasked main loop
#pragma unroll
    for (int p = 0; p < D; ++p) {
      const int i = base + p;
      const float4 wv = wreg[p];
      const f16x8 h = hreg[p];
      const int nk = rs + i + D;
      if (nk < re) {
        wreg[p] = *(const float4*)&wexp[(size_t)nk * 4];
        const int s = sreg[p];
        hreg[p] = *(const f16x8*)&xsrc[(size_t)s * 128 + col0];
      }
      const int nk2 = rs + i + 2 * D;
      if (nk2 < re) sreg[p] = csr[nk2];
      Z0 += wv.x; Z1 += wv.y; Z2 += wv.z; Z3 += wv.w;
#pragma unroll
      for (int j = 0; j < 8; ++j) {
        const float hv = (float)h[j];
        acc0[j] += wv.x * hv;
        acc1[j] += wv.y * hv;
        acc2[j] += wv.z * hv;
        acc3[j] += wv.w * hv;
      }
    }
  }
  for (; base < maxdeg; base += D) {  // masked tail
#pragma unroll
    for (int p = 0; p < D; ++p) {
      const int i = base + p;
      const bool act = i < deg;
      const float4 wv = wreg[p];
      const float w0 = act ? wv.x : 0.f;
      const float w1 = act ? wv.y : 0.f;
      const float w2 = act ? wv.z : 0.f;
      const float w3 = act ? wv.w : 0.f;
      const f16x8 h = hreg[p];
      const int nk = rs + i + D;
      if (nk < re) {
        wreg[p] = *(const float4*)&wexp[(size_t)nk * 4];
        const int s = sreg[p];
        hreg[p] = *(const f16x8*)&xsrc[(size_t)s * 128 + col0];
      }
      const int nk2 = rs + i + 2 * D;
      if (nk2 < re) sreg[p] = csr[nk2];
      Z0 += w0; Z1 += w1; Z2 += w2; Z3 += w3;
#pragma unroll
      for (int j = 0; j < 8; ++j) {
        const float hv = (float)h[j];
        acc0[j] += w0 * hv;
        acc1[j] += w1 * hv;
        acc2[j] += w2 * hv;
        acc3[j] += w3 * hv;
      }
    }
  }

  const float i0 = 1.f / (Z0 + 1e-16f);
  const float i1 = 1.f / (Z1 + 1e-16f);
  const float i2 = 1.f / (Z2 + 1e-16f);
  const float i3 = 1.f / (Z3 + 1e-16f);
  f16* orow = aggb + (size_t)node * 512 + col0;
  f16x8 o0, o1, o2, o3;
#pragma unroll
  for (int j = 0; j < 8; ++j) {
    o0[j] = (f16)(acc0[j] * i0);
    o1[j] = (f16)(acc1[j] * i1);
    o2[j] = (f16)(acc2[j] * i2);
    o3[j] = (f16)(acc3[j] * i3);
  }
  *(f16x8*)&orow[0]   = o0;
  *(f16x8*)&orow[128] = o1;
  *(f16x8*)&orow[256] = o2;
  *(f16x8*)&orow[384] = o3;
}

// ---------------------------------------------------------------------------
// layer-2 aggregation, 4 nodes/wave, reversed order, inline edge weights,
// fused bias/ELU/L2-normalize.
// ---------------------------------------------------------------------------
__global__ __launch_bounds__(256) void aggregate2(
    const f16* __restrict__ hsrc, const float* __restrict__ as2,
    const float* __restrict__ ad2, const int* __restrict__ rowstart,
    const int* __restrict__ csr, const int* __restrict__ order,
    const float* __restrict__ bias, float* __restrict__ out) {
  const int wave = (blockIdx.x * blockDim.x + threadIdx.x) >> 6;
  const int lane = threadIdx.x & 63;
  const int g16 = lane >> 4, l16 = lane & 15;
  const int node = order[N_NODES - 1 - (wave * 4 + g16)];
  const int col0 = l16 * 8;
  const int rs = rowstart[node];
  const int re = rowstart[node + 1];
  const int deg = re - rs;
  const float ad = ad2[node];

  int maxdeg = deg, mindeg = deg;
  maxdeg = max(maxdeg, __shfl_xor(maxdeg, 16));
  maxdeg = max(maxdeg, __shfl_xor(maxdeg, 32));
  mindeg = min(mindeg, __shfl_xor(mindeg, 16));
  mindeg = min(mindeg, __shfl_xor(mindeg, 32));

  constexpr int D = 6;
  int sreg[D];
  float areg[D];
  f16x8 hreg[D];
#pragma unroll
  for (int p = 0; p < D; ++p) {
    const int k = rs + p;
    const int kc = (k < re) ? k : (re - 1);
    const int s = csr[kc];
    areg[p] = as2[s];
    hreg[p] = *(const f16x8*)&hsrc[(size_t)s * 128 + col0];
    const int k2 = rs + D + p;
    sreg[p] = csr[(k2 < re) ? k2 : (re - 1)];
  }

  float acc[8] = {};
  float Z = 0.f;
  int base = 0;
  for (; base + D <= mindeg; base += D) {  // unmasked main loop
#pragma unroll
    for (int p = 0; p < D; ++p) {
      const int i = base + p;
      const float w = __expf(lrelu(areg[p] + ad));
      const f16x8 h = hreg[p];
      const int nk = rs + i + D;
      if (nk < re) {
        const int s = sreg[p];
        areg[p] = as2[s];
        hreg[p] = *(const f16x8*)&hsrc[(size_t)s * 128 + col0];
      }
      const int nk2 = rs + i + 2 * D;
      if (nk2 < re) sreg[p] = csr[nk2];
      Z += w;
#pragma unroll
      for (int j = 0; j < 8; ++j) acc[j] += w * (float)h[j];
    }
  }
  for (; base < maxdeg; base += D) {  // masked tail
#pragma unroll
    for (int p = 0; p < D; ++p) {
      const int i = base + p;
      const bool act = i < deg;
      const float w = act ? __expf(lrelu(areg[p] + ad)) : 0.f;
      const f16x8 h = hreg[p];
      const int nk = rs + i + D;
      if (nk < re) {
        const int s = sreg[p];
        areg[p] = as2[s];
        hreg[p] = *(const f16x8*)&hsrc[(size_t)s * 128 + col0];
      }
      const int nk2 = rs + i + 2 * D;
      if (nk2 < re) sreg[p] = csr[nk2];
      Z += w;
#pragma unroll
      for (int j = 0; j < 8; ++j) acc[j] += w * (float)h[j];
    }
  }
  const float inv = 1.f / (Z + 1e-16f);

  float4 ba = *(const float4*)&bias[col0];
  float4 bb = *(const float4*)&bias[col0 + 4];
  const float bv[8] = {ba.x, ba.y, ba.z, ba.w, bb.x, bb.y, bb.z, bb.w};
  float v[8];
  float ss = 0.f;
#pragma unroll
  for (int j = 0; j < 8; ++j) {
    float t = acc[j] * inv + bv[j];
    t = t > 0.f ? t : (__expf(t) - 1.f);
    v[j] = t;
    ss += t * t;
  }
  ss += __shfl_xor(ss, 1);
  ss += __shfl_xor(ss, 2);
  ss += __shfl_xor(ss, 4);
  ss += __shfl_xor(ss, 8);
  const float invn = 1.f / fmaxf(sqrtf(ss), 1e-12f);
  float* orow = out + (size_t)node * 128 + col0;
  float4 oa = make_float4(v[0] * invn, v[1] * invn, v[2] * invn, v[3] * invn);
  float4 ob = make_float4(v[4] * invn, v[5] * invn, v[6] * invn, v[7] * invn);
  *(float4*)&orow[0] = oa;
  *(float4*)&orow[4] = ob;
}

// ---------------------------------------------------------------------------
extern "C" void kernel_launch(void* const* d_in, const int* in_sizes, int n_in,
                              void* d_out, int out_size, void* d_ws, size_t ws_size,
                              hipStream_t stream) {
  const float* x        = (const float*)d_in[0];
  const int*   ei       = (const int*)d_in[1];
  const float* W1       = (const float*)d_in[2];
  const float* att_src1 = (const float*)d_in[3];
  const float* att_dst1 = (const float*)d_in[4];
  const float* bias1    = (const float*)d_in[5];
  const float* W2       = (const float*)d_in[6];
  const float* att_src2 = (const float*)d_in[7];
  const float* att_dst2 = (const float*)d_in[8];
  const float* bias2    = (const float*)d_in[9];
  float* out = (float*)d_out;

  char* ws = (char*)d_ws;
  size_t off = 0;
  auto alloc = [&](size_t bytes) {
    char* p = ws + off;
    off = (off + bytes + 255) & ~(size_t)255;
    return p;
  };
  f16* xb    = (f16*)alloc(sizeof(f16) * (size_t)M_PAD * 128);
  f16* w1t   = (f16*)alloc(sizeof(f16) * 512 * 128);
  f16* w2t   = (f16*)alloc(sizeof(f16) * 128 * 512);
  f16* aggb  = (f16*)alloc(sizeof(f16) * (size_t)M_PAD * 512);
  f16* out1b = (f16*)alloc(sizeof(f16) * (size_t)M_PAD * 512);
  float* V1s = (float*)alloc(sizeof(float) * 512);
  float* V1d = (float*)alloc(sizeof(float) * 512);
  float* V2s = (float*)alloc(sizeof(float) * 512);
  float* V2d = (float*)alloc(sizeof(float) * 512);
  float* as1 = (float*)alloc(sizeof(float) * N_NODES * 4);
  float* ad1 = (float*)alloc(sizeof(float) * N_NODES * 4);
  float* as2 = (float*)alloc(sizeof(float) * M_PAD);
  float* ad2 = (float*)alloc(sizeof(float) * M_PAD);
  float* wexp1 = (float*)alloc(sizeof(float) * (size_t)TOT_EDGES * 4);
  int* rowstart = (int*)alloc(sizeof(int) * (SCAN_PAD + 4));
  int* deg      = (int*)alloc(sizeof(int) * SCAN_PAD);
  int* cursor   = (int*)alloc(sizeof(int) * SCAN_PAD);
  int* bsum     = (int*)alloc(sizeof(int) * 64);
  int* blkcnt   = (int*)alloc(sizeof(int) * 128 * NBLK);
  int* order    = (int*)alloc(sizeof(int) * N_NODES);
  int* csr      = (int*)alloc(sizeof(int) * TOT_EDGES);
  f16* h2b = aggb;  // alias: aggb dead after the head-GEMMs

  const int agrid = (N_NODES / 4) * 64 / 256;  // 3125 blocks, 4 nodes/wave

  // 1: zero degree array
  zero_int<<<(SCAN_PAD + 255) / 256, 256, 0, stream>>>(deg, SCAN_PAD);
  // 2: degree count + weight/projection prep (disjoint block ranges)
  count_weights<<<CNT_BLKS + 768, 256, 0, stream>>>(
      ei, deg, W1, W2, att_src1, att_dst1, att_src2, att_dst2,
      w1t, w2t, V1s, V1d, V2s, V2d);
  // 3: degree histogram + block scan  |  prep_x (xb, a1, aggb pad)
  histscan_prepx<<<NBLK + M_PAD / 4, 256, 0, stream>>>(
      deg, rowstart, bsum, blkcnt, x, xb, V1s, V1d, as1, ad1, aggb);
  // 4: offsets (recomputed in-block) + rowstart/cursor finalize + order scatter
  scatter_addoff2<<<NBLK, 256, 0, stream>>>(rowstart, bsum, cursor, deg, blkcnt, order);
  // 5: CSR fill + layer-1 edge weights
  fill_w1<<<CNT_BLKS, 256, 0, stream>>>(ei, cursor, as1, ad1, csr, wexp1);
  // 6: layer-1 aggregation (input space, heavy-first)
  aggregate1x<<<agrid, 256, 0, stream>>>(xb, wexp1, rowstart, csr, order, aggb);
  // 7: 4 per-head GEMMs (+bias+ELU)
  gemm_bt<128, true, false><<<dim3(M_PAD / 128, 4), 256, 0, stream>>>(
      aggb, 512, w1t, 128, out1b, 512, bias1, nullptr, nullptr, nullptr, nullptr);
  // 8: layer-2 GEMM (with fused a2 = out1 . V2)
  gemm_bt<512, false, true><<<dim3(M_PAD / 128, 1), 256, 0, stream>>>(
      out1b, 512, w2t, 512, h2b, 128, nullptr, V2s, V2d, as2, ad2);
  // 9: layer-2 aggregation + bias/ELU/L2-normalize (heavy-first)
  aggregate2<<<agrid, 256, 0, stream>>>(h2b, as2, ad2, rowstart, csr, order, bias2, out);
}